// Round 1
// baseline (996.780 us; speedup 1.0000x reference)
//
#include <hip/hip_runtime.h>
#include <hip/hip_bf16.h>
#include <math.h>

// ---------------------------------------------------------------------------
// ResidualBlock (PyG GMMConv/MoNet + BatchNorm1d training mode + ELU)
//   h = elu(bn1(conv1(x)));  h2 = bn2(conv2(h));  s = bns(convs(x))
//   out = elu(h2 + s)
// Decomposition per conv:
//   XG[n,k,c] = x @ g ;  XR[n,c] = x @ root + bias
//   per edge e: w[k] = exp(-0.5*sum_d (attr-mu)^2 / (eps+sigma^2))
//               agg[dst,c] += sum_k w[k]*XG[src,k,c]
//   out[n,c] = agg[n,c]/max(cnt[n],1) + XR[n,c]
// BN stats (biased var over nodes) accumulated in conv epilogue.
// ---------------------------------------------------------------------------

#define ELU(v) ((v) > 0.f ? (v) : (__expf(v) - 1.f))

// ---- GEMM: 192 output cols per node = [xg(160) | xr(32)], wave-per-node ----
__global__ __launch_bounds__(256) void gemm192(
    const float* __restrict__ x, const float* __restrict__ g,
    const float* __restrict__ root, const float* __restrict__ bias,
    float* __restrict__ XG, float* __restrict__ XR, int N)
{
    const int lane = threadIdx.x & 63;
    const int wid = (blockIdx.x * blockDim.x + threadIdx.x) >> 6;
    const int nwaves = (gridDim.x * blockDim.x) >> 6;
    const bool cIsG = lane < 32;

    // weights register-resident: cols lane, lane+64, lane+128 (the latter
    // maps to root for lanes >= 32)
    float wA[32], wB[32], wC[32];
#pragma unroll
    for (int i = 0; i < 32; ++i) {
        wA[i] = g[i * 160 + lane];
        wB[i] = g[i * 160 + 64 + lane];
        wC[i] = cIsG ? g[i * 160 + 128 + lane] : root[i * 32 + (lane - 32)];
    }
    const float bv = cIsG ? 0.f : bias[lane - 32];

    for (int n = wid; n < N; n += nwaves) {
        const float4* xr4 = (const float4*)(x + (size_t)n * 32);
        float a0 = 0.f, a1 = 0.f, a2 = 0.f;
#pragma unroll
        for (int q = 0; q < 8; ++q) {
            float4 xv = xr4[q];
            const int i = q * 4;
            a0 = fmaf(xv.x, wA[i + 0], a0); a0 = fmaf(xv.y, wA[i + 1], a0);
            a0 = fmaf(xv.z, wA[i + 2], a0); a0 = fmaf(xv.w, wA[i + 3], a0);
            a1 = fmaf(xv.x, wB[i + 0], a1); a1 = fmaf(xv.y, wB[i + 1], a1);
            a1 = fmaf(xv.z, wB[i + 2], a1); a1 = fmaf(xv.w, wB[i + 3], a1);
            a2 = fmaf(xv.x, wC[i + 0], a2); a2 = fmaf(xv.y, wC[i + 1], a2);
            a2 = fmaf(xv.z, wC[i + 2], a2); a2 = fmaf(xv.w, wC[i + 3], a2);
        }
        XG[(size_t)n * 160 + lane] = a0;
        XG[(size_t)n * 160 + 64 + lane] = a1;
        if (cIsG) XG[(size_t)n * 160 + 128 + lane] = a2;
        else      XR[(size_t)n * 32 + (lane - 32)] = a2 + bv;
    }
}

// ---- GEMM for shortcut (K=1): 64 cols = [xg(32) | xr(32)] ----
__global__ __launch_bounds__(256) void gemm64(
    const float* __restrict__ x, const float* __restrict__ g,
    const float* __restrict__ root, const float* __restrict__ bias,
    float* __restrict__ XG, float* __restrict__ XR, int N)
{
    const int lane = threadIdx.x & 63;
    const int wid = (blockIdx.x * blockDim.x + threadIdx.x) >> 6;
    const int nwaves = (gridDim.x * blockDim.x) >> 6;
    const bool cIsG = lane < 32;

    float wA[32];
#pragma unroll
    for (int i = 0; i < 32; ++i)
        wA[i] = cIsG ? g[i * 32 + lane] : root[i * 32 + (lane - 32)];
    const float bv = cIsG ? 0.f : bias[lane - 32];

    for (int n = wid; n < N; n += nwaves) {
        const float4* xr4 = (const float4*)(x + (size_t)n * 32);
        float a0 = 0.f;
#pragma unroll
        for (int q = 0; q < 8; ++q) {
            float4 xv = xr4[q];
            const int i = q * 4;
            a0 = fmaf(xv.x, wA[i + 0], a0); a0 = fmaf(xv.y, wA[i + 1], a0);
            a0 = fmaf(xv.z, wA[i + 2], a0); a0 = fmaf(xv.w, wA[i + 3], a0);
        }
        if (cIsG) XG[(size_t)n * 32 + lane] = a0;
        else      XR[(size_t)n * 32 + (lane - 32)] = a0 + bv;
    }
}

// ---- in-degree histogram (shared across all three convs) ----
__global__ void degree_k(const int* __restrict__ dst, int* __restrict__ cnt, int E)
{
    int e = blockIdx.x * blockDim.x + threadIdx.x;
    if (e < E) atomicAdd(&cnt[dst[e]], 1);
}

// ---- edge message + scatter: 8 edges per 256-thread block, 32 lanes/edge ----
template <int K>
__global__ __launch_bounds__(256) void edge_k(
    const float* __restrict__ XG, const int* __restrict__ ei,
    const float* __restrict__ attr, const float* __restrict__ mu,
    const float* __restrict__ sigma, float* __restrict__ agg, int E)
{
    __shared__ float s_mu[K * 3], s_inv[K * 3];
    const int tid = threadIdx.x;
    if (tid < K * 3) {
        s_mu[tid] = mu[tid];
        float s = sigma[tid];
        s_inv[tid] = 1.0f / (1e-15f + s * s);
    }
    __syncthreads();

    const int c = tid & 31;
    const int e = blockIdx.x * (blockDim.x >> 5) + (tid >> 5);
    if (e >= E) return;

    const int src = ei[e];
    const int dst = ei[E + e];
    const float a0 = attr[(size_t)e * 3 + 0];
    const float a1 = attr[(size_t)e * 3 + 1];
    const float a2 = attr[(size_t)e * 3 + 2];

    const float* xg = XG + (size_t)src * (K * 32);
    float acc = 0.f;
#pragma unroll
    for (int k = 0; k < K; ++k) {
        float d0 = a0 - s_mu[k * 3 + 0];
        float d1 = a1 - s_mu[k * 3 + 1];
        float d2 = a2 - s_mu[k * 3 + 2];
        float q = d0 * d0 * s_inv[k * 3 + 0] + d1 * d1 * s_inv[k * 3 + 1]
                + d2 * d2 * s_inv[k * 3 + 2];
        float w = __expf(-0.5f * q);
        acc = fmaf(w, xg[k * 32 + c], acc);
    }
    atomicAdd(&agg[(size_t)dst * 32 + c], acc);
}

// ---- conv epilogue: out = agg/max(cnt,1) + xr; accumulate BN sum/sumsq ----
__global__ __launch_bounds__(256) void epi_k(
    const float* __restrict__ agg, const int* __restrict__ cnt,
    const float* __restrict__ xr, float* __restrict__ out,
    float* __restrict__ stats /* [64] = sum[32], sumsq[32] */, int N)
{
    __shared__ float s_sum[32], s_sq[32];
    const int tid = threadIdx.x;
    if (tid < 32) { s_sum[tid] = 0.f; s_sq[tid] = 0.f; }
    __syncthreads();

    const int c = tid & 31;
    const int total = N * 32;
    float lsum = 0.f, lsq = 0.f;
    for (int idx = blockIdx.x * blockDim.x + tid; idx < total;
         idx += gridDim.x * blockDim.x) {
        int n = idx >> 5;
        float v = agg[idx] / fmaxf((float)cnt[n], 1.0f) + xr[idx];
        out[idx] = v;
        lsum += v; lsq += v * v;
    }
    // fold lanes l and l+32 (same channel, different node slots)
    lsum += __shfl_xor(lsum, 32);
    lsq  += __shfl_xor(lsq, 32);
    if ((tid & 63) < 32) { atomicAdd(&s_sum[c], lsum); atomicAdd(&s_sq[c], lsq); }
    __syncthreads();
    if (tid < 32) {
        atomicAdd(&stats[tid], s_sum[tid]);
        atomicAdd(&stats[32 + tid], s_sq[tid]);
    }
}

// ---- BN coefficients: scale = gamma*rsqrt(var+eps), shift = beta - m*scale ----
__global__ void coef_k(const float* __restrict__ stats, const float* __restrict__ gam,
                       const float* __restrict__ bet, float* __restrict__ coef,
                       float invN)
{
    int c = threadIdx.x;
    if (c < 32) {
        float m = stats[c] * invN;
        float v = fmaxf(stats[32 + c] * invN - m * m, 0.f);
        float sc = gam[c] * rsqrtf(v + 1e-5f);
        coef[c] = sc;
        coef[32 + c] = bet[c] - m * sc;
    }
}

// ---- elementwise: h = elu(bn(in)) ----
__global__ __launch_bounds__(256) void bn_elu_k(
    const float* __restrict__ in, const float* __restrict__ coef,
    float* __restrict__ out, int total)
{
    int idx = blockIdx.x * blockDim.x + threadIdx.x;
    if (idx >= total) return;
    int c = idx & 31;
    float v = in[idx] * coef[c] + coef[32 + c];
    out[idx] = ELU(v);
}

// ---- final: out = elu(bn2(o2) + bns(os)) ----
__global__ __launch_bounds__(256) void final_k(
    const float* __restrict__ o2, const float* __restrict__ os,
    const float* __restrict__ c2, const float* __restrict__ cs,
    float* __restrict__ out, int total)
{
    int idx = blockIdx.x * blockDim.x + threadIdx.x;
    if (idx >= total) return;
    int c = idx & 31;
    float v = o2[idx] * c2[c] + c2[32 + c] + os[idx] * cs[c] + cs[32 + c];
    out[idx] = ELU(v);
}

extern "C" void kernel_launch(void* const* d_in, const int* in_sizes, int n_in,
                              void* d_out, int out_size, void* d_ws, size_t ws_size,
                              hipStream_t stream)
{
    const float* x      = (const float*)d_in[0];
    const int*   ei     = (const int*)d_in[1];
    const float* attr   = (const float*)d_in[2];
    const float* g1     = (const float*)d_in[3];
    const float* mu1    = (const float*)d_in[4];
    const float* sig1   = (const float*)d_in[5];
    const float* root1  = (const float*)d_in[6];
    const float* b1     = (const float*)d_in[7];
    const float* gam1   = (const float*)d_in[8];
    const float* bet1   = (const float*)d_in[9];
    const float* g2     = (const float*)d_in[10];
    const float* mu2    = (const float*)d_in[11];
    const float* sig2   = (const float*)d_in[12];
    const float* root2  = (const float*)d_in[13];
    const float* b2     = (const float*)d_in[14];
    const float* gam2   = (const float*)d_in[15];
    const float* bet2   = (const float*)d_in[16];
    const float* gs     = (const float*)d_in[17];
    const float* mus    = (const float*)d_in[18];
    const float* sigs   = (const float*)d_in[19];
    const float* roots  = (const float*)d_in[20];
    const float* bs     = (const float*)d_in[21];
    const float* gams   = (const float*)d_in[22];
    const float* bets   = (const float*)d_in[23];

    const int N = in_sizes[0] / 32;
    const int E = in_sizes[1] / 2;
    const int total = N * 32;

    // workspace carve-up (256-B aligned)
    char* ws = (char*)d_ws;
    size_t off = 0;
    auto carve = [&](size_t bytes) {
        void* p = ws + off;
        off = (off + bytes + 255) & ~(size_t)255;
        return p;
    };
    float* XG    = (float*)carve((size_t)N * 160 * 4);
    float* XR    = (float*)carve((size_t)N * 32 * 4);
    float* AGG   = (float*)carve((size_t)N * 32 * 4);
    float* H     = (float*)carve((size_t)N * 32 * 4);   // out1, then h in place
    float* OUT2  = (float*)carve((size_t)N * 32 * 4);
    float* OUTS  = (float*)carve((size_t)N * 32 * 4);
    int*   CNT   = (int*)carve((size_t)N * 4);
    float* STATS = (float*)carve(6 * 64 * 4);
    float* stats1 = STATS;        float* stats2 = STATS + 64;  float* statss = STATS + 128;
    float* coef1  = STATS + 192;  float* coef2  = STATS + 256; float* coefs  = STATS + 320;
    (void)ws_size; (void)n_in; (void)out_size;

    const int eb = (E + 7) / 8;                 // edge blocks (8 edges / block)
    const int ew = (total + 255) / 256;         // elementwise blocks
    const float invN = 1.0f / (float)N;

    hipMemsetAsync(CNT, 0, (size_t)N * 4, stream);
    hipMemsetAsync(STATS, 0, 3 * 64 * 4, stream);
    degree_k<<<(E + 255) / 256, 256, 0, stream>>>(ei + E, CNT, E);

    // ---- conv1 (x -> H) ----
    gemm192<<<1024, 256, 0, stream>>>(x, g1, root1, b1, XG, XR, N);
    hipMemsetAsync(AGG, 0, (size_t)total * 4, stream);
    edge_k<5><<<eb, 256, 0, stream>>>(XG, ei, attr, mu1, sig1, AGG, E);
    epi_k<<<1024, 256, 0, stream>>>(AGG, CNT, XR, H, stats1, N);
    coef_k<<<1, 64, 0, stream>>>(stats1, gam1, bet1, coef1, invN);
    bn_elu_k<<<ew, 256, 0, stream>>>(H, coef1, H, total);

    // ---- conv2 (H -> OUT2) ----
    gemm192<<<1024, 256, 0, stream>>>(H, g2, root2, b2, XG, XR, N);
    hipMemsetAsync(AGG, 0, (size_t)total * 4, stream);
    edge_k<5><<<eb, 256, 0, stream>>>(XG, ei, attr, mu2, sig2, AGG, E);
    epi_k<<<1024, 256, 0, stream>>>(AGG, CNT, XR, OUT2, stats2, N);

    // ---- shortcut (x -> OUTS) ----
    gemm64<<<1024, 256, 0, stream>>>(x, gs, roots, bs, XG, XR, N);
    hipMemsetAsync(AGG, 0, (size_t)total * 4, stream);
    edge_k<1><<<eb, 256, 0, stream>>>(XG, ei, attr, mus, sigs, AGG, E);
    epi_k<<<1024, 256, 0, stream>>>(AGG, CNT, XR, OUTS, statss, N);

    // ---- BN coefs + fused residual ELU ----
    coef_k<<<1, 64, 0, stream>>>(stats2, gam2, bet2, coef2, invN);
    coef_k<<<1, 64, 0, stream>>>(statss, gams, bets, coefs, invN);
    final_k<<<ew, 256, 0, stream>>>(OUT2, OUTS, coef2, coefs, (float*)d_out, total);
}

// Round 2
// 858.987 us; speedup vs baseline: 1.1604x; 1.1604x over previous
//
#include <hip/hip_runtime.h>
#include <hip/hip_bf16.h>
#include <math.h>

// ---------------------------------------------------------------------------
// ResidualBlock (PyG GMMConv/MoNet + BN train + ELU), CSR-restructured.
//  - CSR by dst (degree -> scan -> fill payload {src,a0,a1,a2})
//  - XG projection tables stored bf16; conv1(K=5)+shortcut(K=1) share one
//    [n][192]-bf16 row (384 B, 3 aligned 128B lines) so one gather pass
//    serves both. conv2 reuses the same buffer ([0:160] section).
//  - gather pass: 16 lanes per dst, lane covers 2 channels; per 16-edge
//    chunk each lane computes ONE edge's Gaussian weights, then weights/src
//    are distributed via __shfl(width=16). Register accumulation, single
//    write per dst. Mean + root/bias + BN-stat accumulation fused.
// ---------------------------------------------------------------------------

#define ELU(v) ((v) > 0.f ? (v) : (__expf(v) - 1.f))

__device__ inline ushort f2bf(float f) {
    __hip_bfloat16 h = __float2bfloat16(f);
    return *reinterpret_cast<ushort*>(&h);
}
__device__ inline float bflo(unsigned u) { return __uint_as_float(u << 16); }
__device__ inline float bfhi(unsigned u) { return __uint_as_float(u & 0xffff0000u); }

// ---- GEMM: per node writes XG[0:160] bf16 (stride 192) + XR fp32 ----------
// MODE BN: input row transformed h = elu(in*sc+sh) (conv2 reading conv1 out)
template <bool BN>
__global__ __launch_bounds__(256) void gemm192(
    const float* __restrict__ xin, const float* __restrict__ coef,
    const float* __restrict__ g, const float* __restrict__ root,
    const float* __restrict__ bias,
    ushort* __restrict__ XG, float* __restrict__ XR, int xr_stride, int N)
{
    const int lane = threadIdx.x & 63;
    const int wid = (blockIdx.x * blockDim.x + threadIdx.x) >> 6;
    const int nwaves = (gridDim.x * blockDim.x) >> 6;
    const bool cIsG = lane < 32;

    float wA[32], wB[32], wC[32];
#pragma unroll
    for (int i = 0; i < 32; ++i) {
        wA[i] = g[i * 160 + lane];
        wB[i] = g[i * 160 + 64 + lane];
        wC[i] = cIsG ? g[i * 160 + 128 + lane] : root[i * 32 + (lane - 32)];
    }
    const float bv = cIsG ? 0.f : bias[lane - 32];

    for (int n = wid; n < N; n += nwaves) {
        const float4* xr4 = (const float4*)(xin + (size_t)n * 32);
        float a0 = 0.f, a1 = 0.f, a2 = 0.f;
#pragma unroll
        for (int q = 0; q < 8; ++q) {
            float4 xv = xr4[q];
            float xs[4] = {xv.x, xv.y, xv.z, xv.w};
#pragma unroll
            for (int j = 0; j < 4; ++j) {
                const int i = q * 4 + j;
                float v = xs[j];
                if (BN) { v = v * coef[i] + coef[32 + i]; v = ELU(v); }
                a0 = fmaf(v, wA[i], a0);
                a1 = fmaf(v, wB[i], a1);
                a2 = fmaf(v, wC[i], a2);
            }
        }
        ushort* xgrow = XG + (size_t)n * 192;
        xgrow[lane] = f2bf(a0);
        xgrow[64 + lane] = f2bf(a1);
        if (cIsG) xgrow[128 + lane] = f2bf(a2);
        else      XR[(size_t)n * xr_stride + (lane - 32)] = a2 + bv;
    }
}

// ---- shortcut GEMM: writes XG[160:192] bf16 + XRA[32:64] fp32 -------------
__global__ __launch_bounds__(256) void gemm64s(
    const float* __restrict__ x, const float* __restrict__ g,
    const float* __restrict__ root, const float* __restrict__ bias,
    ushort* __restrict__ XG, float* __restrict__ XRA, int N)
{
    const int lane = threadIdx.x & 63;
    const int wid = (blockIdx.x * blockDim.x + threadIdx.x) >> 6;
    const int nwaves = (gridDim.x * blockDim.x) >> 6;
    const bool cIsG = lane < 32;

    float wA[32];
#pragma unroll
    for (int i = 0; i < 32; ++i)
        wA[i] = cIsG ? g[i * 32 + lane] : root[i * 32 + (lane - 32)];
    const float bv = cIsG ? 0.f : bias[lane - 32];

    for (int n = wid; n < N; n += nwaves) {
        const float4* xr4 = (const float4*)(x + (size_t)n * 32);
        float a0 = 0.f;
#pragma unroll
        for (int q = 0; q < 8; ++q) {
            float4 xv = xr4[q];
            const int i = q * 4;
            a0 = fmaf(xv.x, wA[i + 0], a0); a0 = fmaf(xv.y, wA[i + 1], a0);
            a0 = fmaf(xv.z, wA[i + 2], a0); a0 = fmaf(xv.w, wA[i + 3], a0);
        }
        if (cIsG) XG[(size_t)n * 192 + 160 + lane] = f2bf(a0);
        else      XRA[(size_t)n * 64 + 32 + (lane - 32)] = a0 + bv;
    }
}

// ---- CSR build ------------------------------------------------------------
__global__ void degree_k(const int* __restrict__ dst, int* __restrict__ deg, int E)
{
    int e = blockIdx.x * blockDim.x + threadIdx.x;
    if (e < E) atomicAdd(&deg[dst[e]], 1);
}

#define SCHUNK 128
__global__ void scan_part(const int* __restrict__ deg, int* __restrict__ part,
                          int N, int nchunk)
{
    int t = blockIdx.x * blockDim.x + threadIdx.x;
    if (t >= nchunk) return;
    int s = 0, base = t * SCHUNK, end = min(base + SCHUNK, N);
    for (int i = base; i < end; ++i) s += deg[i];
    part[t] = s;
}

__global__ void scan_top(int* __restrict__ part, int nchunk)
{
    __shared__ int sh[1024];
    int t = threadIdx.x;
    int v = (t < nchunk) ? part[t] : 0;
    sh[t] = v;
    __syncthreads();
    for (int off = 1; off < 1024; off <<= 1) {
        int x = (t >= off) ? sh[t - off] : 0;
        __syncthreads();
        sh[t] += x;
        __syncthreads();
    }
    if (t < nchunk) part[t] = sh[t] - v;   // exclusive
}

__global__ void scan_write(const int* __restrict__ deg, const int* __restrict__ part,
                           int* __restrict__ row_ptr, int N, int nchunk)
{
    int t = blockIdx.x * blockDim.x + threadIdx.x;
    if (t >= nchunk) return;
    int run = part[t], base = t * SCHUNK, end = min(base + SCHUNK, N);
    for (int i = base; i < end; ++i) { row_ptr[i] = run; run += deg[i]; }
    if (end == N) row_ptr[N] = run;
}

__global__ void fill_k(const int* __restrict__ ei, const float* __restrict__ attr,
                       const int* __restrict__ row_ptr, int* __restrict__ cur,
                       float4* __restrict__ payload, int E)
{
    int e = blockIdx.x * blockDim.x + threadIdx.x;
    if (e >= E) return;
    int s = ei[e], d = ei[E + e];
    int pos = row_ptr[d] + atomicAdd(&cur[d], 1);
    payload[pos] = make_float4(__int_as_float(s),
                               attr[(size_t)e * 3 + 0],
                               attr[(size_t)e * 3 + 1],
                               attr[(size_t)e * 3 + 2]);
}

// ---- fused gather + mean + root + BN-stats --------------------------------
// 16 lanes per dst, lane l covers channels (2l, 2l+1).
template <bool HAS_S>
__global__ __launch_bounds__(256) void gather_k(
    const ushort* __restrict__ XG,      // [n][192] bf16
    const float* __restrict__ XR,       // [n][xr_stride]
    const float4* __restrict__ payload,
    const int* __restrict__ row_ptr,
    const float* __restrict__ mu_m, const float* __restrict__ sg_m,
    const float* __restrict__ mu_s, const float* __restrict__ sg_s,
    float* __restrict__ out_m, float* __restrict__ out_s,
    float* __restrict__ stats_m, float* __restrict__ stats_s,
    int N, int ntiles)
{
    // uniform scalar loads of gaussian params
    float mm[15], im[15];
#pragma unroll
    for (int i = 0; i < 15; ++i) {
        mm[i] = mu_m[i];
        float s = sg_m[i];
        im[i] = 1.0f / (1e-15f + s * s);
    }
    float ms[3], is[3];
    if (HAS_S) {
#pragma unroll
        for (int i = 0; i < 3; ++i) {
            ms[i] = mu_s[i];
            float s = sg_s[i];
            is[i] = 1.0f / (1e-15f + s * s);
        }
    }

    const int l = threadIdx.x & 15;     // lane in group (channel pair)
    const int g = threadIdx.x >> 4;     // group (dst within tile)

    float2 ps1 = {0.f, 0.f}, pq1 = {0.f, 0.f};
    float2 psS = {0.f, 0.f}, pqS = {0.f, 0.f};

    for (int tile = blockIdx.x; tile < ntiles; tile += gridDim.x) {
        const int dst = tile * 16 + g;
        float2 acc1 = {0.f, 0.f}, accS = {0.f, 0.f};
        int rp0 = 0, deg = 0;
        if (dst < N) { rp0 = row_ptr[dst]; deg = row_ptr[dst + 1] - rp0; }

        for (int base = 0; base < deg; base += 16) {
            const int idx = base + l;
            float w[5] = {0, 0, 0, 0, 0};
            float wS = 0.f;
            int src = 0;
            if (idx < deg) {
                float4 p = payload[rp0 + idx];
                src = __float_as_int(p.x);
#pragma unroll
                for (int k = 0; k < 5; ++k) {
                    float d0 = p.y - mm[k * 3 + 0];
                    float d1 = p.z - mm[k * 3 + 1];
                    float d2 = p.w - mm[k * 3 + 2];
                    float q = d0 * d0 * im[k * 3 + 0] + d1 * d1 * im[k * 3 + 1]
                            + d2 * d2 * im[k * 3 + 2];
                    w[k] = __expf(-0.5f * q);
                }
                if (HAS_S) {
                    float d0 = p.y - ms[0], d1 = p.z - ms[1], d2 = p.w - ms[2];
                    float q = d0 * d0 * is[0] + d1 * d1 * is[1] + d2 * d2 * is[2];
                    wS = __expf(-0.5f * q);
                }
            }
            const int jmax = min(16, deg - base);
            for (int j = 0; j < jmax; ++j) {
                const int sj = __shfl(src, j, 16);
                float wj[5];
#pragma unroll
                for (int k = 0; k < 5; ++k) wj[k] = __shfl(w[k], j, 16);
                const unsigned* row = (const unsigned*)(XG + (size_t)sj * 192);
#pragma unroll
                for (int k = 0; k < 5; ++k) {
                    unsigned u = row[k * 16 + l];
                    acc1.x = fmaf(wj[k], bflo(u), acc1.x);
                    acc1.y = fmaf(wj[k], bfhi(u), acc1.y);
                }
                if (HAS_S) {
                    float wsj = __shfl(wS, j, 16);
                    unsigned u = row[80 + l];
                    accS.x = fmaf(wsj, bflo(u), accS.x);
                    accS.y = fmaf(wsj, bfhi(u), accS.y);
                }
            }
        }

        if (dst < N) {
            const float inv = 1.0f / fmaxf((float)deg, 1.0f);
            const float* xr = XR + (size_t)dst * (HAS_S ? 64 : 32);
            float2 v1;
            v1.x = acc1.x * inv + xr[2 * l];
            v1.y = acc1.y * inv + xr[2 * l + 1];
            out_m[(size_t)dst * 32 + 2 * l] = v1.x;
            out_m[(size_t)dst * 32 + 2 * l + 1] = v1.y;
            ps1.x += v1.x; ps1.y += v1.y;
            pq1.x += v1.x * v1.x; pq1.y += v1.y * v1.y;
            if (HAS_S) {
                float2 vs;
                vs.x = accS.x * inv + xr[32 + 2 * l];
                vs.y = accS.y * inv + xr[32 + 2 * l + 1];
                out_s[(size_t)dst * 32 + 2 * l] = vs.x;
                out_s[(size_t)dst * 32 + 2 * l + 1] = vs.y;
                psS.x += vs.x; psS.y += vs.y;
                pqS.x += vs.x * vs.x; pqS.y += vs.y * vs.y;
            }
        }
    }

    // block-level stat reduction -> 8-way-spread global partials
    __shared__ float sred[64];
    const int tid = threadIdx.x;
    const int spread = (blockIdx.x & 7) * 64;

    {   // main
        if (tid < 64) sred[tid] = 0.f;
        __syncthreads();
        atomicAdd(&sred[2 * l], ps1.x);
        atomicAdd(&sred[2 * l + 1], ps1.y);
        atomicAdd(&sred[32 + 2 * l], pq1.x);
        atomicAdd(&sred[32 + 2 * l + 1], pq1.y);
        __syncthreads();
        if (tid < 64) atomicAdd(&stats_m[spread + tid], sred[tid]);
        __syncthreads();
    }
    if (HAS_S) {
        if (tid < 64) sred[tid] = 0.f;
        __syncthreads();
        atomicAdd(&sred[2 * l], psS.x);
        atomicAdd(&sred[2 * l + 1], psS.y);
        atomicAdd(&sred[32 + 2 * l], pqS.x);
        atomicAdd(&sred[32 + 2 * l + 1], pqS.y);
        __syncthreads();
        if (tid < 64) atomicAdd(&stats_s[spread + tid], sred[tid]);
    }
}

// ---- BN coefficients (reduce 8 partials) ----------------------------------
__global__ void coef_k(const float* __restrict__ stats, const float* __restrict__ gam,
                       const float* __restrict__ bet, float* __restrict__ coef,
                       float invN)
{
    int c = threadIdx.x;
    if (c < 32) {
        float s = 0.f, q = 0.f;
        for (int p = 0; p < 8; ++p) { s += stats[p * 64 + c]; q += stats[p * 64 + 32 + c]; }
        float m = s * invN;
        float v = fmaxf(q * invN - m * m, 0.f);
        float sc = gam[c] * rsqrtf(v + 1e-5f);
        coef[c] = sc;
        coef[32 + c] = bet[c] - m * sc;
    }
}

// ---- final: out = elu(bn2(o2) + bns(os)) ----------------------------------
__global__ __launch_bounds__(256) void final_k(
    const float* __restrict__ o2, const float* __restrict__ os,
    const float* __restrict__ c2, const float* __restrict__ cs,
    float* __restrict__ out, int total)
{
    int idx = blockIdx.x * blockDim.x + threadIdx.x;
    if (idx >= total) return;
    int c = idx & 31;
    float v = o2[idx] * c2[c] + c2[32 + c] + os[idx] * cs[c] + cs[32 + c];
    out[idx] = ELU(v);
}

extern "C" void kernel_launch(void* const* d_in, const int* in_sizes, int n_in,
                              void* d_out, int out_size, void* d_ws, size_t ws_size,
                              hipStream_t stream)
{
    const float* x      = (const float*)d_in[0];
    const int*   ei     = (const int*)d_in[1];
    const float* attr   = (const float*)d_in[2];
    const float* g1     = (const float*)d_in[3];
    const float* mu1    = (const float*)d_in[4];
    const float* sig1   = (const float*)d_in[5];
    const float* root1  = (const float*)d_in[6];
    const float* b1     = (const float*)d_in[7];
    const float* gam1   = (const float*)d_in[8];
    const float* bet1   = (const float*)d_in[9];
    const float* g2     = (const float*)d_in[10];
    const float* mu2    = (const float*)d_in[11];
    const float* sig2   = (const float*)d_in[12];
    const float* root2  = (const float*)d_in[13];
    const float* b2     = (const float*)d_in[14];
    const float* gam2   = (const float*)d_in[15];
    const float* bet2   = (const float*)d_in[16];
    const float* gs     = (const float*)d_in[17];
    const float* mus    = (const float*)d_in[18];
    const float* sigs   = (const float*)d_in[19];
    const float* roots  = (const float*)d_in[20];
    const float* bs     = (const float*)d_in[21];
    const float* gams   = (const float*)d_in[22];
    const float* bets   = (const float*)d_in[23];

    const int N = in_sizes[0] / 32;
    const int E = in_sizes[1] / 2;
    const int total = N * 32;
    const int nchunk = (N + SCHUNK - 1) / SCHUNK;   // <= 1024 required
    const int ntiles = (N + 15) / 16;

    char* ws = (char*)d_ws;
    size_t off = 0;
    auto carve = [&](size_t bytes) {
        void* p = ws + off;
        off = (off + bytes + 255) & ~(size_t)255;
        return p;
    };
    ushort* XGA    = (ushort*)carve((size_t)N * 192 * 2);   // 38.4 MB (shared A/B)
    float*  XRA    = (float*)carve((size_t)N * 64 * 4);     // 25.6 MB (XR2 aliases, stride 32)
    float*  OUT1   = (float*)carve((size_t)N * 32 * 4);
    float*  OUT2   = (float*)carve((size_t)N * 32 * 4);
    float*  OUTS   = (float*)carve((size_t)N * 32 * 4);
    float4* PAY    = (float4*)carve((size_t)E * 16);        // 25.6 MB
    int*    ROWP   = (int*)carve((size_t)(N + 1) * 4);
    int*    DEG    = (int*)carve((size_t)N * 4);
    int*    CUR    = (int*)carve((size_t)N * 4);
    int*    PART   = (int*)carve(1024 * 4);
    float*  STATS  = (float*)carve(3 * 512 * 4);            // 3 convs x [8][64]
    float*  COEF   = (float*)carve(3 * 64 * 4);
    float* stats1 = STATS, *stats2 = STATS + 512, *statsS = STATS + 1024;
    float* coef1 = COEF, *coef2 = COEF + 64, *coefS = COEF + 128;
    (void)ws_size; (void)n_in; (void)out_size;

    const float invN = 1.0f / (float)N;
    const int eb = (E + 255) / 256;
    const int ew = (total + 255) / 256;

    hipMemsetAsync(DEG, 0, (size_t)N * 4, stream);
    hipMemsetAsync(CUR, 0, (size_t)N * 4, stream);
    hipMemsetAsync(STATS, 0, 3 * 512 * 4, stream);

    // CSR build
    degree_k<<<eb, 256, 0, stream>>>(ei + E, DEG, E);
    scan_part<<<(nchunk + 255) / 256, 256, 0, stream>>>(DEG, PART, N, nchunk);
    scan_top<<<1, 1024, 0, stream>>>(PART, nchunk);
    scan_write<<<(nchunk + 255) / 256, 256, 0, stream>>>(DEG, PART, ROWP, N, nchunk);
    fill_k<<<eb, 256, 0, stream>>>(ei, attr, ROWP, CUR, PAY, E);

    // projections for pass A (conv1 + shortcut share XGA/XRA)
    gemm192<false><<<1024, 256, 0, stream>>>(x, nullptr, g1, root1, b1, XGA, XRA, 64, N);
    gemm64s<<<512, 256, 0, stream>>>(x, gs, roots, bs, XGA, XRA, N);

    // pass A: conv1 out -> OUT1, shortcut out -> OUTS
    gather_k<true><<<2048, 256, 0, stream>>>(XGA, XRA, PAY, ROWP,
        mu1, sig1, mus, sigs, OUT1, OUTS, stats1, statsS, N, ntiles);
    coef_k<<<1, 64, 0, stream>>>(stats1, gam1, bet1, coef1, invN);
    coef_k<<<1, 64, 0, stream>>>(statsS, gams, bets, coefS, invN);

    // conv2 projection (reads OUT1 with fused BN+ELU), reuses XGA/XRA
    gemm192<true><<<1024, 256, 0, stream>>>(OUT1, coef1, g2, root2, b2, XGA, XRA, 32, N);

    // pass B: conv2 out -> OUT2
    gather_k<false><<<2048, 256, 0, stream>>>(XGA, XRA, PAY, ROWP,
        mu2, sig2, nullptr, nullptr, OUT2, nullptr, stats2, nullptr, N, ntiles);
    coef_k<<<1, 64, 0, stream>>>(stats2, gam2, bet2, coef2, invN);

    final_k<<<ew, 256, 0, stream>>>(OUT2, OUTS, coef2, coefS, (float*)d_out, total);
}

// Round 3
// 722.213 us; speedup vs baseline: 1.3802x; 1.1894x over previous
//
#include <hip/hip_runtime.h>
#include <hip/hip_bf16.h>
#include <math.h>

// ---------------------------------------------------------------------------
// ResidualBlock (PyG GMMConv/MoNet + BN train + ELU), CSR + permuted-gather.
//  - CSR by dst; payload {src,a0,a1,a2} per edge.
//  - XGP projection rows in bf16, LANE-PERMUTED layout: per node,
//      part0: lane l -> uint4  at dword  l*4      (k = 0..3, channels 2l,2l+1)
//      part1: lane l -> uint2  at dword 64 + l*2  (k = 4, shortcut)   [pass A]
//             lane l -> uint   at dword 64 + l    (k = 4)             [pass B]
//    so a 16-lane group fetches a whole row with 2 aligned vector loads/lane.
//  - gather: 16 lanes/dst; per 16-edge chunk lane l computes edge l's
//    Gaussian weights -> LDS (2xb128); j-loop (unrolled x4) reads broadcast
//    weights + 2 vector loads/edge; register accumulation; mean + root +
//    BN-stats fused in epilogue.
// ---------------------------------------------------------------------------

#define ELU(v) ((v) > 0.f ? (v) : (__expf(v) - 1.f))

__device__ inline ushort f2bf(float f) {
    __hip_bfloat16 h = __float2bfloat16(f);
    return *reinterpret_cast<ushort*>(&h);
}
__device__ inline float bflo(unsigned u) { return __uint_as_float(u << 16); }
__device__ inline float bfhi(unsigned u) { return __uint_as_float(u & 0xffff0000u); }

// ---- GEMM: per node writes XGP (permuted bf16) + XR fp32 ------------------
// SLOTS=6: row stride 192 ushorts (conv g in k=0..4; k=5 written by gemm64s)
// SLOTS=5: row stride 160 ushorts (conv g only)
// BN: input transformed v = elu(in*sc+sh) first (conv2 reading conv1 out)
template <int SLOTS, bool BN>
__global__ __launch_bounds__(256) void gemm192(
    const float* __restrict__ xin, const float* __restrict__ coef,
    const float* __restrict__ g, const float* __restrict__ root,
    const float* __restrict__ bias,
    ushort* __restrict__ XGP, float* __restrict__ XR, int xr_stride, int N)
{
    const int lane = threadIdx.x & 63;
    const int wid = (blockIdx.x * blockDim.x + threadIdx.x) >> 6;
    const int nwaves = (gridDim.x * blockDim.x) >> 6;
    const bool cIsG = lane < 32;
    const int c0 = lane & 31;
    const int k0 = lane >> 5;          // a0 -> k0, a1 -> k0+2, a2 -> k=4

    float wA[32], wB[32], wC[32];
#pragma unroll
    for (int i = 0; i < 32; ++i) {
        wA[i] = g[i * 160 + lane];
        wB[i] = g[i * 160 + 64 + lane];
        wC[i] = cIsG ? g[i * 160 + 128 + lane] : root[i * 32 + (lane - 32)];
    }
    const float bv = cIsG ? 0.f : bias[lane - 32];

    // permuted ushort indices (constant per lane)
    const int i0 = ((c0 >> 1) * 4 + k0) * 2 + (c0 & 1);
    const int i1 = ((c0 >> 1) * 4 + k0 + 2) * 2 + (c0 & 1);
    const int i2 = (SLOTS == 6 ? (64 + (c0 >> 1) * 2) : (64 + (c0 >> 1))) * 2 + (c0 & 1);

    for (int n = wid; n < N; n += nwaves) {
        const float4* xr4 = (const float4*)(xin + (size_t)n * 32);
        float a0 = 0.f, a1 = 0.f, a2 = 0.f;
#pragma unroll
        for (int q = 0; q < 8; ++q) {
            float4 xv = xr4[q];
            float xs[4] = {xv.x, xv.y, xv.z, xv.w};
#pragma unroll
            for (int j = 0; j < 4; ++j) {
                const int i = q * 4 + j;
                float v = xs[j];
                if (BN) { v = v * coef[i] + coef[32 + i]; v = ELU(v); }
                a0 = fmaf(v, wA[i], a0);
                a1 = fmaf(v, wB[i], a1);
                a2 = fmaf(v, wC[i], a2);
            }
        }
        ushort* r = XGP + (size_t)n * (SLOTS * 32);
        r[i0] = f2bf(a0);
        r[i1] = f2bf(a1);
        if (cIsG) r[i2] = f2bf(a2);
        else      XR[(size_t)n * xr_stride + (lane - 32)] = a2 + bv;
    }
}

// ---- shortcut GEMM: writes k=5 slot of SLOTS=6 rows + XRA[32:64] ----------
__global__ __launch_bounds__(256) void gemm64s(
    const float* __restrict__ x, const float* __restrict__ g,
    const float* __restrict__ root, const float* __restrict__ bias,
    ushort* __restrict__ XGP, float* __restrict__ XRA, int N)
{
    const int lane = threadIdx.x & 63;
    const int wid = (blockIdx.x * blockDim.x + threadIdx.x) >> 6;
    const int nwaves = (gridDim.x * blockDim.x) >> 6;
    const bool cIsG = lane < 32;
    const int c = lane & 31;

    float wA[32];
#pragma unroll
    for (int i = 0; i < 32; ++i)
        wA[i] = cIsG ? g[i * 32 + c] : root[i * 32 + c];
    const float bv = cIsG ? 0.f : bias[c];
    const int i5 = (64 + (c >> 1) * 2 + 1) * 2 + (c & 1);

    for (int n = wid; n < N; n += nwaves) {
        const float4* xr4 = (const float4*)(x + (size_t)n * 32);
        float a0 = 0.f;
#pragma unroll
        for (int q = 0; q < 8; ++q) {
            float4 xv = xr4[q];
            const int i = q * 4;
            a0 = fmaf(xv.x, wA[i + 0], a0); a0 = fmaf(xv.y, wA[i + 1], a0);
            a0 = fmaf(xv.z, wA[i + 2], a0); a0 = fmaf(xv.w, wA[i + 3], a0);
        }
        if (cIsG) XGP[(size_t)n * 192 + i5] = f2bf(a0);
        else      XRA[(size_t)n * 64 + 32 + c] = a0 + bv;
    }
}

// ---- CSR build ------------------------------------------------------------
__global__ void degree_k(const int* __restrict__ dst, int* __restrict__ deg, int E)
{
    int e = blockIdx.x * blockDim.x + threadIdx.x;
    if (e < E) atomicAdd(&deg[dst[e]], 1);
}

#define SCHUNK 128
__global__ void scan_part(const int* __restrict__ deg, int* __restrict__ part,
                          int N, int nchunk)
{
    int t = blockIdx.x * blockDim.x + threadIdx.x;
    if (t >= nchunk) return;
    int s = 0, base = t * SCHUNK, end = min(base + SCHUNK, N);
    for (int i = base; i < end; ++i) s += deg[i];
    part[t] = s;
}

__global__ void scan_top(int* __restrict__ part, int nchunk)
{
    __shared__ int sh[1024];
    int t = threadIdx.x;
    int v = (t < nchunk) ? part[t] : 0;
    sh[t] = v;
    __syncthreads();
    for (int off = 1; off < 1024; off <<= 1) {
        int x = (t >= off) ? sh[t - off] : 0;
        __syncthreads();
        sh[t] += x;
        __syncthreads();
    }
    if (t < nchunk) part[t] = sh[t] - v;   // exclusive
}

__global__ void scan_write(const int* __restrict__ deg, const int* __restrict__ part,
                           int* __restrict__ row_ptr, int N, int nchunk)
{
    int t = blockIdx.x * blockDim.x + threadIdx.x;
    if (t >= nchunk) return;
    int run = part[t], base = t * SCHUNK, end = min(base + SCHUNK, N);
    for (int i = base; i < end; ++i) { row_ptr[i] = run; run += deg[i]; }
    if (end == N) row_ptr[N] = run;
}

__global__ void fill_k(const int* __restrict__ ei, const float* __restrict__ attr,
                       const int* __restrict__ row_ptr, int* __restrict__ cur,
                       float4* __restrict__ payload, int E)
{
    int e = blockIdx.x * blockDim.x + threadIdx.x;
    if (e >= E) return;
    int s = ei[e], d = ei[E + e];
    int pos = row_ptr[d] + atomicAdd(&cur[d], 1);
    payload[pos] = make_float4(__int_as_float(s),
                               attr[(size_t)e * 3 + 0],
                               attr[(size_t)e * 3 + 1],
                               attr[(size_t)e * 3 + 2]);
}

// ---- fused gather + mean + root + BN-stats --------------------------------
template <bool HAS_S>
__global__ __launch_bounds__(256) void gather_k(
    const unsigned* __restrict__ XGP,   // permuted rows (96 or 80 dwords)
    const float* __restrict__ XR,
    const float4* __restrict__ payload,
    const int* __restrict__ row_ptr,
    const float* __restrict__ mu_m, const float* __restrict__ sg_m,
    const float* __restrict__ mu_s, const float* __restrict__ sg_s,
    float* __restrict__ out_m, float* __restrict__ out_s,
    float* __restrict__ stats_m, float* __restrict__ stats_s,
    int N, int ntiles)
{
    constexpr int ROWDW = HAS_S ? 96 : 80;

    float mm[15], im[15];
#pragma unroll
    for (int i = 0; i < 15; ++i) {
        mm[i] = mu_m[i];
        float s = sg_m[i];
        im[i] = 1.0f / (1e-15f + s * s);
    }
    float ms[3], is[3];
    if (HAS_S) {
#pragma unroll
        for (int i = 0; i < 3; ++i) {
            ms[i] = mu_s[i];
            float s = sg_s[i];
            is[i] = 1.0f / (1e-15f + s * s);
        }
    }

    const int l = threadIdx.x & 15;
    const int g = threadIdx.x >> 4;

    // [group][edge(+1 pad row)][8] : reads are conflict-free broadcasts
    __shared__ float wbuf[16][17][8];

    float2 ps1 = {0.f, 0.f}, pq1 = {0.f, 0.f};
    float2 psS = {0.f, 0.f}, pqS = {0.f, 0.f};

    for (int tile = blockIdx.x; tile < ntiles; tile += gridDim.x) {
        const int dst = tile * 16 + g;
        float2 acc1 = {0.f, 0.f}, accS = {0.f, 0.f};
        int rp0 = 0, deg = 0;
        if (dst < N) { rp0 = row_ptr[dst]; deg = row_ptr[dst + 1] - rp0; }

        auto body = [&](int j) {
            const float4 a = *(const float4*)&wbuf[g][j][0];
            const float4 b = *(const float4*)&wbuf[g][j][4];
            const int sj = __float_as_int(a.x);
            const unsigned* row = XGP + (size_t)sj * ROWDW;
            const uint4 u = *(const uint4*)(row + l * 4);
            acc1.x = fmaf(a.y, bflo(u.x), acc1.x); acc1.y = fmaf(a.y, bfhi(u.x), acc1.y);
            acc1.x = fmaf(a.z, bflo(u.y), acc1.x); acc1.y = fmaf(a.z, bfhi(u.y), acc1.y);
            acc1.x = fmaf(a.w, bflo(u.z), acc1.x); acc1.y = fmaf(a.w, bfhi(u.z), acc1.y);
            acc1.x = fmaf(b.x, bflo(u.w), acc1.x); acc1.y = fmaf(b.x, bfhi(u.w), acc1.y);
            if (HAS_S) {
                const uint2 t = *(const uint2*)(row + 64 + l * 2);
                acc1.x = fmaf(b.y, bflo(t.x), acc1.x); acc1.y = fmaf(b.y, bfhi(t.x), acc1.y);
                accS.x = fmaf(b.z, bflo(t.y), accS.x); accS.y = fmaf(b.z, bfhi(t.y), accS.y);
            } else {
                const unsigned t = row[64 + l];
                acc1.x = fmaf(b.y, bflo(t), acc1.x); acc1.y = fmaf(b.y, bfhi(t), acc1.y);
            }
        };

        for (int base = 0; base < deg; base += 16) {
            const int nj = min(16, deg - base);
            if (l < nj) {
                float4 p = payload[rp0 + base + l];
                float w[5], wS = 0.f;
#pragma unroll
                for (int k = 0; k < 5; ++k) {
                    float d0 = p.y - mm[k * 3 + 0];
                    float d1 = p.z - mm[k * 3 + 1];
                    float d2 = p.w - mm[k * 3 + 2];
                    float q = d0 * d0 * im[k * 3 + 0] + d1 * d1 * im[k * 3 + 1]
                            + d2 * d2 * im[k * 3 + 2];
                    w[k] = __expf(-0.5f * q);
                }
                if (HAS_S) {
                    float d0 = p.y - ms[0], d1 = p.z - ms[1], d2 = p.w - ms[2];
                    float q = d0 * d0 * is[0] + d1 * d1 * is[1] + d2 * d2 * is[2];
                    wS = __expf(-0.5f * q);
                }
                float4* wp = (float4*)&wbuf[g][l][0];
                wp[0] = make_float4(p.x, w[0], w[1], w[2]);
                wp[1] = make_float4(w[3], w[4], wS, 0.f);
            }
            int j = 0;
            for (; j + 3 < nj; j += 4) { body(j); body(j + 1); body(j + 2); body(j + 3); }
            for (; j < nj; ++j) body(j);
        }

        if (dst < N) {
            const float inv = 1.0f / fmaxf((float)deg, 1.0f);
            const float2* xr = (const float2*)(XR + (size_t)dst * (HAS_S ? 64 : 32));
            float2 x1 = xr[l];
            float2 v1;
            v1.x = acc1.x * inv + x1.x;
            v1.y = acc1.y * inv + x1.y;
            *(float2*)(out_m + (size_t)dst * 32 + 2 * l) = v1;
            ps1.x += v1.x; ps1.y += v1.y;
            pq1.x += v1.x * v1.x; pq1.y += v1.y * v1.y;
            if (HAS_S) {
                float2 xs = xr[16 + l];
                float2 vs;
                vs.x = accS.x * inv + xs.x;
                vs.y = accS.y * inv + xs.y;
                *(float2*)(out_s + (size_t)dst * 32 + 2 * l) = vs;
                psS.x += vs.x; psS.y += vs.y;
                pqS.x += vs.x * vs.x; pqS.y += vs.y * vs.y;
            }
        }
    }

    // block-level stat reduction -> 8-way-spread global partials
    __shared__ float sred[64];
    const int tid = threadIdx.x;
    const int spread = (blockIdx.x & 7) * 64;

    {
        if (tid < 64) sred[tid] = 0.f;
        __syncthreads();
        atomicAdd(&sred[2 * l], ps1.x);
        atomicAdd(&sred[2 * l + 1], ps1.y);
        atomicAdd(&sred[32 + 2 * l], pq1.x);
        atomicAdd(&sred[32 + 2 * l + 1], pq1.y);
        __syncthreads();
        if (tid < 64) atomicAdd(&stats_m[spread + tid], sred[tid]);
        __syncthreads();
    }
    if (HAS_S) {
        if (tid < 64) sred[tid] = 0.f;
        __syncthreads();
        atomicAdd(&sred[2 * l], psS.x);
        atomicAdd(&sred[2 * l + 1], psS.y);
        atomicAdd(&sred[32 + 2 * l], pqS.x);
        atomicAdd(&sred[32 + 2 * l + 1], pqS.y);
        __syncthreads();
        if (tid < 64) atomicAdd(&stats_s[spread + tid], sred[tid]);
    }
}

// ---- BN coefficients (reduce 8 partials) ----------------------------------
__global__ void coef_k(const float* __restrict__ stats, const float* __restrict__ gam,
                       const float* __restrict__ bet, float* __restrict__ coef,
                       float invN)
{
    int c = threadIdx.x;
    if (c < 32) {
        float s = 0.f, q = 0.f;
        for (int p = 0; p < 8; ++p) { s += stats[p * 64 + c]; q += stats[p * 64 + 32 + c]; }
        float m = s * invN;
        float v = fmaxf(q * invN - m * m, 0.f);
        float sc = gam[c] * rsqrtf(v + 1e-5f);
        coef[c] = sc;
        coef[32 + c] = bet[c] - m * sc;
    }
}

// ---- final: out = elu(bn2(o2) + bns(os)) ----------------------------------
__global__ __launch_bounds__(256) void final_k(
    const float* __restrict__ o2, const float* __restrict__ os,
    const float* __restrict__ c2, const float* __restrict__ cs,
    float* __restrict__ out, int total)
{
    int idx = blockIdx.x * blockDim.x + threadIdx.x;
    if (idx >= total) return;
    int c = idx & 31;
    float v = o2[idx] * c2[c] + c2[32 + c] + os[idx] * cs[c] + cs[32 + c];
    out[idx] = ELU(v);
}

extern "C" void kernel_launch(void* const* d_in, const int* in_sizes, int n_in,
                              void* d_out, int out_size, void* d_ws, size_t ws_size,
                              hipStream_t stream)
{
    const float* x      = (const float*)d_in[0];
    const int*   ei     = (const int*)d_in[1];
    const float* attr   = (const float*)d_in[2];
    const float* g1     = (const float*)d_in[3];
    const float* mu1    = (const float*)d_in[4];
    const float* sig1   = (const float*)d_in[5];
    const float* root1  = (const float*)d_in[6];
    const float* b1     = (const float*)d_in[7];
    const float* gam1   = (const float*)d_in[8];
    const float* bet1   = (const float*)d_in[9];
    const float* g2     = (const float*)d_in[10];
    const float* mu2    = (const float*)d_in[11];
    const float* sig2   = (const float*)d_in[12];
    const float* root2  = (const float*)d_in[13];
    const float* b2     = (const float*)d_in[14];
    const float* gam2   = (const float*)d_in[15];
    const float* bet2   = (const float*)d_in[16];
    const float* gs     = (const float*)d_in[17];
    const float* mus    = (const float*)d_in[18];
    const float* sigs   = (const float*)d_in[19];
    const float* roots  = (const float*)d_in[20];
    const float* bs     = (const float*)d_in[21];
    const float* gams   = (const float*)d_in[22];
    const float* bets   = (const float*)d_in[23];

    const int N = in_sizes[0] / 32;
    const int E = in_sizes[1] / 2;
    const int total = N * 32;
    const int nchunk = (N + SCHUNK - 1) / SCHUNK;   // <= 1024 required
    const int ntiles = (N + 15) / 16;

    char* ws = (char*)d_ws;
    size_t off = 0;
    auto carve = [&](size_t bytes) {
        void* p = ws + off;
        off = (off + bytes + 255) & ~(size_t)255;
        return p;
    };
    ushort* XGP    = (ushort*)carve((size_t)N * 192 * 2);   // 38.4 MB (A reuses for B)
    float*  XRA    = (float*)carve((size_t)N * 64 * 4);     // pass A stride 64 / B stride 32
    float*  OUT1   = (float*)carve((size_t)N * 32 * 4);
    float*  OUT2   = (float*)carve((size_t)N * 32 * 4);
    float*  OUTS   = (float*)carve((size_t)N * 32 * 4);
    float4* PAY    = (float4*)carve((size_t)E * 16);        // 25.6 MB
    int*    ROWP   = (int*)carve((size_t)(N + 1) * 4);
    int*    DEG    = (int*)carve((size_t)N * 4);
    int*    CUR    = (int*)carve((size_t)N * 4);
    int*    PART   = (int*)carve(1024 * 4);
    float*  STATS  = (float*)carve(3 * 512 * 4);            // 3 convs x [8][64]
    float*  COEF   = (float*)carve(3 * 64 * 4);
    float* stats1 = STATS, *stats2 = STATS + 512, *statsS = STATS + 1024;
    float* coef1 = COEF, *coef2 = COEF + 64, *coefS = COEF + 128;
    (void)ws_size; (void)n_in; (void)out_size;

    const float invN = 1.0f / (float)N;
    const int eb = (E + 255) / 256;
    const int ew = (total + 255) / 256;

    hipMemsetAsync(DEG, 0, (size_t)N * 4, stream);
    hipMemsetAsync(CUR, 0, (size_t)N * 4, stream);
    hipMemsetAsync(STATS, 0, 3 * 512 * 4, stream);

    // CSR build
    degree_k<<<eb, 256, 0, stream>>>(ei + E, DEG, E);
    scan_part<<<(nchunk + 255) / 256, 256, 0, stream>>>(DEG, PART, N, nchunk);
    scan_top<<<1, 1024, 0, stream>>>(PART, nchunk);
    scan_write<<<(nchunk + 255) / 256, 256, 0, stream>>>(DEG, PART, ROWP, N, nchunk);
    fill_k<<<eb, 256, 0, stream>>>(ei, attr, ROWP, CUR, PAY, E);

    // projections for pass A (conv1 k=0..4 + shortcut k=5 share XGP/XRA)
    gemm192<6, false><<<1024, 256, 0, stream>>>(x, nullptr, g1, root1, b1, XGP, XRA, 64, N);
    gemm64s<<<512, 256, 0, stream>>>(x, gs, roots, bs, XGP, XRA, N);

    // pass A: conv1 -> OUT1, shortcut -> OUTS
    gather_k<true><<<ntiles, 256, 0, stream>>>((const unsigned*)XGP, XRA, PAY, ROWP,
        mu1, sig1, mus, sigs, OUT1, OUTS, stats1, statsS, N, ntiles);
    coef_k<<<1, 64, 0, stream>>>(stats1, gam1, bet1, coef1, invN);
    coef_k<<<1, 64, 0, stream>>>(statsS, gams, bets, coefS, invN);

    // conv2 projection (fused BN+ELU on OUT1), SLOTS=5 rows
    gemm192<5, true><<<1024, 256, 0, stream>>>(OUT1, coef1, g2, root2, b2, XGP, XRA, 32, N);

    // pass B: conv2 -> OUT2
    gather_k<false><<<ntiles, 256, 0, stream>>>((const unsigned*)XGP, XRA, PAY, ROWP,
        mu2, sig2, nullptr, nullptr, OUT2, nullptr, stats2, nullptr, N, ntiles);
    coef_k<<<1, 64, 0, stream>>>(stats2, gam2, bet2, coef2, invN);

    final_k<<<ew, 256, 0, stream>>>(OUT2, OUTS, coef2, coefS, (float*)d_out, total);
}

// Round 4
// 570.863 us; speedup vs baseline: 1.7461x; 1.2651x over previous
//
#include <hip/hip_runtime.h>
#include <hip/hip_bf16.h>
#include <math.h>

// ---------------------------------------------------------------------------
// ResidualBlock (PyG GMMConv/MoNet + BN train + ELU), v4: linearity-reordered.
//   msg[dst] = sum_k w_ek (x G_k)[src]  ==  sum_k G_k^T (sum_e w_ek x[src])
//   => gather only needs x[src] (64 B bf16 row, 6.4 MB table ~ L2-resident),
//      accumulating agg[dst][k][i] (k=0..4 conv + slot5 shortcut in pass A).
//   The 160->32 transform (agg @ G) is a dense bf16 GEMM done with MFMA
//   16x16x32 (10 mfma / 16 nodes), fused with mean, +root, BN stats.
// Pipeline: CSR build -> prepA(XB,XR1,XRS) -> gatherA -> transformA(MFMA)
//   -> coef1/coefS -> prepB(h=elu(bn1(out1)) -> XB2, XR2) -> gatherB
//   -> transformB -> coef2 -> final.
// ---------------------------------------------------------------------------

#define ELU(v) ((v) > 0.f ? (v) : (__expf(v) - 1.f))

using short8  = __attribute__((ext_vector_type(8))) short;
using floatx4 = __attribute__((ext_vector_type(4))) float;

__device__ inline ushort f2bf(float f) {
    __hip_bfloat16 h = __float2bfloat16(f);
    return *reinterpret_cast<ushort*>(&h);
}
__device__ inline float bflo(unsigned u) { return __uint_as_float(u << 16); }
__device__ inline float bfhi(unsigned u) { return __uint_as_float(u & 0xffff0000u); }
__device__ inline unsigned pack_bf2(float lo, float hi) {
    return ((unsigned)f2bf(hi) << 16) | (unsigned)f2bf(lo);
}

// ---- prep A: XB = bf16(x); XR[n][0:32]=x@root1+b1; XR[n][32:64]=x@roots+bs --
__global__ __launch_bounds__(256) void prep_a(
    const float* __restrict__ x,
    const float* __restrict__ root1, const float* __restrict__ b1,
    const float* __restrict__ roots, const float* __restrict__ bs,
    unsigned* __restrict__ XB, float* __restrict__ XR, int N)
{
    const int lane = threadIdx.x & 63;
    const int wid = (blockIdx.x * blockDim.x + threadIdx.x) >> 6;
    const int nwaves = (gridDim.x * blockDim.x) >> 6;
    const int c = lane & 31;

    float wR[32];
#pragma unroll
    for (int i = 0; i < 32; ++i)
        wR[i] = (lane < 32) ? root1[i * 32 + c] : roots[i * 32 + c];
    const float bv = (lane < 32) ? b1[c] : bs[c];

    for (int n = wid; n < N; n += nwaves) {
        const float4* xr4 = (const float4*)(x + (size_t)n * 32);
        float a = 0.f;
#pragma unroll
        for (int q = 0; q < 8; ++q) {
            float4 xv = xr4[q];
            const int i = q * 4;
            a = fmaf(xv.x, wR[i + 0], a); a = fmaf(xv.y, wR[i + 1], a);
            a = fmaf(xv.z, wR[i + 2], a); a = fmaf(xv.w, wR[i + 3], a);
        }
        XR[(size_t)n * 64 + lane] = a + bv;
        if (lane < 16) {
            float2 p = *(const float2*)(x + (size_t)n * 32 + lane * 2);
            XB[(size_t)n * 16 + lane] = pack_bf2(p.x, p.y);
        }
    }
}

// ---- prep B: h = elu(bn1(out1)); XB=bf16(h); XR[n*64+c] = h@root2+b2 -------
__global__ __launch_bounds__(256) void prep_b(
    const float* __restrict__ out1, const float* __restrict__ coef,
    const float* __restrict__ root2, const float* __restrict__ b2,
    unsigned* __restrict__ XB, float* __restrict__ XR, int N)
{
    const int lane = threadIdx.x & 63;
    const int wid = (blockIdx.x * blockDim.x + threadIdx.x) >> 6;
    const int nwaves = (gridDim.x * blockDim.x) >> 6;
    const int c = lane & 31;

    float wR[32];
#pragma unroll
    for (int i = 0; i < 32; ++i) wR[i] = root2[i * 32 + c];
    const float bv = b2[c];

    for (int n = wid; n < N; n += nwaves) {
        if (lane < 32) {
            const float4* xr4 = (const float4*)(out1 + (size_t)n * 32);
            float a = 0.f;
#pragma unroll
            for (int q = 0; q < 8; ++q) {
                float4 xv = xr4[q];
                float xs[4] = {xv.x, xv.y, xv.z, xv.w};
#pragma unroll
                for (int j = 0; j < 4; ++j) {
                    const int i = q * 4 + j;
                    float v = xs[j] * coef[i] + coef[32 + i];
                    v = ELU(v);
                    a = fmaf(v, wR[i], a);
                }
            }
            XR[(size_t)n * 64 + c] = a + bv;
        } else if (lane < 48) {
            const int l2 = lane - 32;
            float2 p = *(const float2*)(out1 + (size_t)n * 32 + l2 * 2);
            float v0 = p.x * coef[2 * l2] + coef[32 + 2 * l2];
            float v1 = p.y * coef[2 * l2 + 1] + coef[32 + 2 * l2 + 1];
            v0 = ELU(v0); v1 = ELU(v1);
            XB[(size_t)n * 16 + l2] = pack_bf2(v0, v1);
        }
    }
}

// ---- CSR build ------------------------------------------------------------
__global__ void degree_k(const int* __restrict__ dst, int* __restrict__ deg, int E)
{
    int e = blockIdx.x * blockDim.x + threadIdx.x;
    if (e < E) atomicAdd(&deg[dst[e]], 1);
}

#define SCHUNK 128
__global__ void scan_part(const int* __restrict__ deg, int* __restrict__ part,
                          int N, int nchunk)
{
    int t = blockIdx.x * blockDim.x + threadIdx.x;
    if (t >= nchunk) return;
    int s = 0, base = t * SCHUNK, end = min(base + SCHUNK, N);
    for (int i = base; i < end; ++i) s += deg[i];
    part[t] = s;
}

__global__ void scan_top(int* __restrict__ part, int nchunk)
{
    __shared__ int sh[1024];
    int t = threadIdx.x;
    int v = (t < nchunk) ? part[t] : 0;
    sh[t] = v;
    __syncthreads();
    for (int off = 1; off < 1024; off <<= 1) {
        int x = (t >= off) ? sh[t - off] : 0;
        __syncthreads();
        sh[t] += x;
        __syncthreads();
    }
    if (t < nchunk) part[t] = sh[t] - v;   // exclusive
}

__global__ void scan_write(const int* __restrict__ deg, const int* __restrict__ part,
                           int* __restrict__ row_ptr, int N, int nchunk)
{
    int t = blockIdx.x * blockDim.x + threadIdx.x;
    if (t >= nchunk) return;
    int run = part[t], base = t * SCHUNK, end = min(base + SCHUNK, N);
    for (int i = base; i < end; ++i) { row_ptr[i] = run; run += deg[i]; }
    if (end == N) row_ptr[N] = run;
}

__global__ void fill_k(const int* __restrict__ ei, const float* __restrict__ attr,
                       const int* __restrict__ row_ptr, int* __restrict__ cur,
                       float4* __restrict__ payload, int E)
{
    int e = blockIdx.x * blockDim.x + threadIdx.x;
    if (e >= E) return;
    int s = ei[e], d = ei[E + e];
    int pos = row_ptr[d] + atomicAdd(&cur[d], 1);
    payload[pos] = make_float4(__int_as_float(s),
                               attr[(size_t)e * 3 + 0],
                               attr[(size_t)e * 3 + 1],
                               attr[(size_t)e * 3 + 2]);
}

// ---- gather: agg[dst][k][i] = sum_e w_ek * x_bf16[src][i] -----------------
// 16 lanes/dst, lane l covers input channels (2l, 2l+1); weights staged in LDS.
template <bool HAS_S>
__global__ __launch_bounds__(256) void gather_k(
    const unsigned* __restrict__ XB,    // [n][16] dwords = 32 bf16 channels
    const float4* __restrict__ payload,
    const int* __restrict__ row_ptr,
    const float* __restrict__ mu_m, const float* __restrict__ sg_m,
    const float* __restrict__ mu_s, const float* __restrict__ sg_s,
    unsigned* __restrict__ AGGb,        // [n][SL][16] dwords (bf16 pairs)
    int N, int ntiles)
{
    constexpr int SL = HAS_S ? 6 : 5;

    float mm[15], im[15];
#pragma unroll
    for (int i = 0; i < 15; ++i) {
        mm[i] = mu_m[i];
        float s = sg_m[i];
        im[i] = 1.0f / (1e-15f + s * s);
    }
    float ms[3], is[3];
    if (HAS_S) {
#pragma unroll
        for (int i = 0; i < 3; ++i) {
            ms[i] = mu_s[i];
            float s = sg_s[i];
            is[i] = 1.0f / (1e-15f + s * s);
        }
    }

    const int l = threadIdx.x & 15;
    const int g = threadIdx.x >> 4;
    __shared__ float wbuf[16][17][8];

    for (int tile = blockIdx.x; tile < ntiles; tile += gridDim.x) {
        const int dst = tile * 16 + g;
        float2 acc[SL];
#pragma unroll
        for (int k = 0; k < SL; ++k) acc[k] = make_float2(0.f, 0.f);

        int rp0 = 0, deg = 0;
        if (dst < N) { rp0 = row_ptr[dst]; deg = row_ptr[dst + 1] - rp0; }

        auto body = [&](int j) {
            const float4 a = *(const float4*)&wbuf[g][j][0];
            const float4 b = *(const float4*)&wbuf[g][j][4];
            const int sj = __float_as_int(a.x);
            const unsigned u = XB[(size_t)sj * 16 + l];
            const float x0 = bflo(u), x1 = bfhi(u);
            acc[0].x = fmaf(a.y, x0, acc[0].x); acc[0].y = fmaf(a.y, x1, acc[0].y);
            acc[1].x = fmaf(a.z, x0, acc[1].x); acc[1].y = fmaf(a.z, x1, acc[1].y);
            acc[2].x = fmaf(a.w, x0, acc[2].x); acc[2].y = fmaf(a.w, x1, acc[2].y);
            acc[3].x = fmaf(b.x, x0, acc[3].x); acc[3].y = fmaf(b.x, x1, acc[3].y);
            acc[4].x = fmaf(b.y, x0, acc[4].x); acc[4].y = fmaf(b.y, x1, acc[4].y);
            if (HAS_S) {
                acc[5].x = fmaf(b.z, x0, acc[5].x); acc[5].y = fmaf(b.z, x1, acc[5].y);
            }
        };

        for (int base = 0; base < deg; base += 16) {
            const int nj = min(16, deg - base);
            if (l < nj) {
                float4 p = payload[rp0 + base + l];
                float w[5], wS = 0.f;
#pragma unroll
                for (int k = 0; k < 5; ++k) {
                    float d0 = p.y - mm[k * 3 + 0];
                    float d1 = p.z - mm[k * 3 + 1];
                    float d2 = p.w - mm[k * 3 + 2];
                    float q = d0 * d0 * im[k * 3 + 0] + d1 * d1 * im[k * 3 + 1]
                            + d2 * d2 * im[k * 3 + 2];
                    w[k] = __expf(-0.5f * q);
                }
                if (HAS_S) {
                    float d0 = p.y - ms[0], d1 = p.z - ms[1], d2 = p.w - ms[2];
                    float q = d0 * d0 * is[0] + d1 * d1 * is[1] + d2 * d2 * is[2];
                    wS = __expf(-0.5f * q);
                }
                float4* wp = (float4*)&wbuf[g][l][0];
                wp[0] = make_float4(p.x, w[0], w[1], w[2]);
                wp[1] = make_float4(w[3], w[4], wS, 0.f);
            }
            int j = 0;
            for (; j + 3 < nj; j += 4) { body(j); body(j + 1); body(j + 2); body(j + 3); }
            for (; j < nj; ++j) body(j);
        }

        if (dst < N) {
            unsigned* out = AGGb + (size_t)dst * (SL * 16) + l;
#pragma unroll
            for (int k = 0; k < SL; ++k)
                out[k * 16] = pack_bf2(acc[k].x, acc[k].y);
        }
    }
}

// ---- transform (MFMA): out = (agg @ G)/deg + XR; BN stats fused -----------
// C = A[N x 160] * B[160 x 32], bf16 mfma 16x16x32.
// A-frag: lane loads A[m=lane&15][k=quad*8+j] -> uint4 of the node's agg row.
// B-frag: B[ks][co]=g[ks][s*32+co]; lane: co=16t+(lane&15), ks=quad*8+j.
// C/D: col=lane&15 (channel within tile), row=quad*4+reg (node within 16).
template <bool HAS_S>
__global__ __launch_bounds__(256) void transform_k(
    const unsigned* __restrict__ AGGb,  // [n][SL*16] dwords
    const int* __restrict__ deg,
    const float* __restrict__ g,        // [32][160]
    const float* __restrict__ gss,      // [32][32] (HAS_S only)
    const float* __restrict__ XR,       // [n][64]: [0:32]=conv, [32:64]=shortcut
    float* __restrict__ out_m, float* __restrict__ out_s,
    float* __restrict__ stats_m, float* __restrict__ stats_s,
    int N)
{
    constexpr int SL = HAS_S ? 6 : 5;
    const int lane = threadIdx.x & 63;
    const int l4 = lane & 15, quad = lane >> 4;
    const int wv = threadIdx.x >> 6;

    // register-resident B fragments (bf16 casts of g / gss)
    short8 Bc[5][2];
#pragma unroll
    for (int s = 0; s < 5; ++s)
#pragma unroll
        for (int t = 0; t < 2; ++t)
#pragma unroll
            for (int j = 0; j < 8; ++j)
                Bc[s][t][j] = (short)f2bf(g[(quad * 8 + j) * 160 + s * 32 + 16 * t + l4]);
    short8 Bs[2];
    if (HAS_S) {
#pragma unroll
        for (int t = 0; t < 2; ++t)
#pragma unroll
            for (int j = 0; j < 8; ++j)
                Bs[t][j] = (short)f2bf(gss[(quad * 8 + j) * 32 + 16 * t + l4]);
    }

    const int ngroups = (N + 15) >> 4;
    float ps0 = 0, pq0 = 0, ps1 = 0, pq1 = 0;
    float psS0 = 0, pqS0 = 0, psS1 = 0, pqS1 = 0;

    for (int grp = blockIdx.x * 4 + wv; grp < ngroups; grp += gridDim.x * 4) {
        const int node0 = grp * 16;
        const int myn = min(node0 + l4, N - 1);      // clamped A-row (safe)
        const unsigned* arow = AGGb + (size_t)myn * (SL * 16) + quad * 4;

        floatx4 acc0 = {0.f, 0.f, 0.f, 0.f}, acc1 = {0.f, 0.f, 0.f, 0.f};
#pragma unroll
        for (int s = 0; s < 5; ++s) {
            const uint4 av = *(const uint4*)(arow + 16 * s);
            const short8 A = *reinterpret_cast<const short8*>(&av);
            acc0 = __builtin_amdgcn_mfma_f32_16x16x32_bf16(A, Bc[s][0], acc0, 0, 0, 0);
            acc1 = __builtin_amdgcn_mfma_f32_16x16x32_bf16(A, Bc[s][1], acc1, 0, 0, 0);
        }
        floatx4 accS0 = {0.f, 0.f, 0.f, 0.f}, accS1 = {0.f, 0.f, 0.f, 0.f};
        if (HAS_S) {
            const uint4 av = *(const uint4*)(arow + 16 * 5);
            const short8 A = *reinterpret_cast<const short8*>(&av);
            accS0 = __builtin_amdgcn_mfma_f32_16x16x32_bf16(A, Bs[0], accS0, 0, 0, 0);
            accS1 = __builtin_amdgcn_mfma_f32_16x16x32_bf16(A, Bs[1], accS1, 0, 0, 0);
        }

#pragma unroll
        for (int r = 0; r < 4; ++r) {
            const int n = node0 + quad * 4 + r;
            if (n < N) {
                const float invd = 1.0f / fmaxf((float)deg[n], 1.0f);
                const float* xr = XR + (size_t)n * 64;
                float v0 = acc0[r] * invd + xr[l4];
                float v1 = acc1[r] * invd + xr[16 + l4];
                out_m[(size_t)n * 32 + l4] = v0;
                out_m[(size_t)n * 32 + 16 + l4] = v1;
                ps0 += v0; pq0 += v0 * v0;
                ps1 += v1; pq1 += v1 * v1;
                if (HAS_S) {
                    float s0 = accS0[r] * invd + xr[32 + l4];
                    float s1 = accS1[r] * invd + xr[48 + l4];
                    out_s[(size_t)n * 32 + l4] = s0;
                    out_s[(size_t)n * 32 + 16 + l4] = s1;
                    psS0 += s0; pqS0 += s0 * s0;
                    psS1 += s1; pqS1 += s1 * s1;
                }
            }
        }
    }

    // block stat reduction -> 8-way-spread global partials
    __shared__ float sred[64];
    const int tid = threadIdx.x;
    const int spread = (blockIdx.x & 7) * 64;
    {
        if (tid < 64) sred[tid] = 0.f;
        __syncthreads();
        atomicAdd(&sred[l4], ps0);       atomicAdd(&sred[16 + l4], ps1);
        atomicAdd(&sred[32 + l4], pq0);  atomicAdd(&sred[48 + l4], pq1);
        __syncthreads();
        if (tid < 64) atomicAdd(&stats_m[spread + tid], sred[tid]);
        __syncthreads();
    }
    if (HAS_S) {
        if (tid < 64) sred[tid] = 0.f;
        __syncthreads();
        atomicAdd(&sred[l4], psS0);      atomicAdd(&sred[16 + l4], psS1);
        atomicAdd(&sred[32 + l4], pqS0); atomicAdd(&sred[48 + l4], pqS1);
        __syncthreads();
        if (tid < 64) atomicAdd(&stats_s[spread + tid], sred[tid]);
    }
}

// ---- BN coefficients (reduce 8 partials) ----------------------------------
__global__ void coef_k(const float* __restrict__ stats, const float* __restrict__ gam,
                       const float* __restrict__ bet, float* __restrict__ coef,
                       float invN)
{
    int c = threadIdx.x;
    if (c < 32) {
        float s = 0.f, q = 0.f;
        for (int p = 0; p < 8; ++p) { s += stats[p * 64 + c]; q += stats[p * 64 + 32 + c]; }
        float m = s * invN;
        float v = fmaxf(q * invN - m * m, 0.f);
        float sc = gam[c] * rsqrtf(v + 1e-5f);
        coef[c] = sc;
        coef[32 + c] = bet[c] - m * sc;
    }
}

// ---- final: out = elu(bn2(o2) + bns(os)) ----------------------------------
__global__ __launch_bounds__(256) void final_k(
    const float* __restrict__ o2, const float* __restrict__ os,
    const float* __restrict__ c2, const float* __restrict__ cs,
    float* __restrict__ out, int total)
{
    int idx = blockIdx.x * blockDim.x + threadIdx.x;
    if (idx >= total) return;
    int c = idx & 31;
    float v = o2[idx] * c2[c] + c2[32 + c] + os[idx] * cs[c] + cs[32 + c];
    out[idx] = ELU(v);
}

extern "C" void kernel_launch(void* const* d_in, const int* in_sizes, int n_in,
                              void* d_out, int out_size, void* d_ws, size_t ws_size,
                              hipStream_t stream)
{
    const float* x      = (const float*)d_in[0];
    const int*   ei     = (const int*)d_in[1];
    const float* attr   = (const float*)d_in[2];
    const float* g1     = (const float*)d_in[3];
    const float* mu1    = (const float*)d_in[4];
    const float* sig1   = (const float*)d_in[5];
    const float* root1  = (const float*)d_in[6];
    const float* b1     = (const float*)d_in[7];
    const float* gam1   = (const float*)d_in[8];
    const float* bet1   = (const float*)d_in[9];
    const float* g2     = (const float*)d_in[10];
    const float* mu2    = (const float*)d_in[11];
    const float* sig2   = (const float*)d_in[12];
    const float* root2  = (const float*)d_in[13];
    const float* b2     = (const float*)d_in[14];
    const float* gam2   = (const float*)d_in[15];
    const float* bet2   = (const float*)d_in[16];
    const float* gs     = (const float*)d_in[17];
    const float* mus    = (const float*)d_in[18];
    const float* sigs   = (const float*)d_in[19];
    const float* roots  = (const float*)d_in[20];
    const float* bs     = (const float*)d_in[21];
    const float* gams   = (const float*)d_in[22];
    const float* bets   = (const float*)d_in[23];

    const int N = in_sizes[0] / 32;
    const int E = in_sizes[1] / 2;
    const int total = N * 32;
    const int nchunk = (N + SCHUNK - 1) / SCHUNK;   // <= 1024 required
    const int ntiles = (N + 15) / 16;

    char* ws = (char*)d_ws;
    size_t off = 0;
    auto carve = [&](size_t bytes) {
        void* p = ws + off;
        off = (off + bytes + 255) & ~(size_t)255;
        return p;
    };
    unsigned* XB   = (unsigned*)carve((size_t)N * 16 * 4);     // 6.4 MB
    unsigned* AGGb = (unsigned*)carve((size_t)N * 96 * 4);     // 38.4 MB (SL=6 max)
    float*  XRA    = (float*)carve((size_t)N * 64 * 4);        // 25.6 MB (reused pass B)
    float*  OUT1   = (float*)carve((size_t)N * 32 * 4);
    float*  OUT2   = (float*)carve((size_t)N * 32 * 4);
    float*  OUTS   = (float*)carve((size_t)N * 32 * 4);
    float4* PAY    = (float4*)carve((size_t)E * 16);           // 25.6 MB
    int*    ROWP   = (int*)carve((size_t)(N + 1) * 4);
    int*    DEG    = (int*)carve((size_t)N * 4);
    int*    CUR    = (int*)carve((size_t)N * 4);
    int*    PART   = (int*)carve(1024 * 4);
    float*  STATS  = (float*)carve(3 * 512 * 4);               // 3 convs x [8][64]
    float*  COEF   = (float*)carve(3 * 64 * 4);
    float* stats1 = STATS, *stats2 = STATS + 512, *statsS = STATS + 1024;
    float* coef1 = COEF, *coef2 = COEF + 64, *coefS = COEF + 128;
    (void)ws_size; (void)n_in; (void)out_size;

    const float invN = 1.0f / (float)N;
    const int eb = (E + 255) / 256;
    const int ew = (total + 255) / 256;

    hipMemsetAsync(DEG, 0, (size_t)N * 4, stream);
    hipMemsetAsync(CUR, 0, (size_t)N * 4, stream);
    hipMemsetAsync(STATS, 0, 3 * 512 * 4, stream);

    // CSR build
    degree_k<<<eb, 256, 0, stream>>>(ei + E, DEG, E);
    scan_part<<<(nchunk + 255) / 256, 256, 0, stream>>>(DEG, PART, N, nchunk);
    scan_top<<<1, 1024, 0, stream>>>(PART, nchunk);
    scan_write<<<(nchunk + 255) / 256, 256, 0, stream>>>(DEG, PART, ROWP, N, nchunk);
    fill_k<<<eb, 256, 0, stream>>>(ei, attr, ROWP, CUR, PAY, E);

    // pass A
    prep_a<<<1024, 256, 0, stream>>>(x, root1, b1, roots, bs, XB, XRA, N);
    gather_k<true><<<ntiles, 256, 0, stream>>>(XB, PAY, ROWP,
        mu1, sig1, mus, sigs, AGGb, N, ntiles);
    transform_k<true><<<1024, 256, 0, stream>>>(AGGb, DEG, g1, gs, XRA,
        OUT1, OUTS, stats1, statsS, N);
    coef_k<<<1, 64, 0, stream>>>(stats1, gam1, bet1, coef1, invN);
    coef_k<<<1, 64, 0, stream>>>(statsS, gams, bets, coefS, invN);

    // pass B
    prep_b<<<1024, 256, 0, stream>>>(OUT1, coef1, root2, b2, XB, XRA, N);
    gather_k<false><<<ntiles, 256, 0, stream>>>(XB, PAY, ROWP,
        mu2, sig2, nullptr, nullptr, AGGb, N, ntiles);
    transform_k<false><<<1024, 256, 0, stream>>>(AGGb, DEG, g2, nullptr, XRA,
        OUT2, nullptr, stats2, nullptr, N);
    coef_k<<<1, 64, 0, stream>>>(stats2, gam2, bet2, coef2, invN);

    final_k<<<ew, 256, 0, stream>>>(OUT2, OUTS, coef2, coefS, (float*)d_out, total);
}